// Round 5
// baseline (2835.483 us; speedup 1.0000x reference)
//
#include <hip/hip_runtime.h>
#include <hip/hip_bf16.h>
#include <math.h>

// Problem constants (fixed by setup_inputs)
#define BSZ    8
#define TSTEPS 10
#define FLEN   10
#define HID    64
#define HW     4096                 // 64*64
#define IMG    (HID * HW)           // 262144
#define OC4    (4 * HID)            // 256 gate channels
#define PADW   66
#define PPIX   (PADW * PADW)        // 4356
#define PADIMG (PPIX * HID)         // padded NHWC plane per batch
#define PADSZ  (BSZ * PADIMG)       // 2230272 bf16 elems per buffer
#define SB     (BSZ * IMG)          // 2097152 floats (one c state)
#define KT_E0  640                  // enc0: 1 x-im2col chunk + 9 h chunks
#define KT_STD 1152                 // 9 x chunks + 9 h chunks

typedef __attribute__((ext_vector_type(8))) short bf16x8;
typedef __attribute__((ext_vector_type(4))) float f32x4;

__device__ __forceinline__ float sigmoidf_(float x) {
    return 1.0f / (1.0f + __expf(-x));
}
__device__ __forceinline__ float tanh_fast(float x) {
    float e = __expf(2.0f * x);
    return 1.0f - 2.0f / (e + 1.0f);     // exact at +-inf saturation
}
__device__ __forceinline__ float bf2f(short u) {
    union { unsigned u; float f; } cv;
    cv.u = ((unsigned)(unsigned short)u) << 16;
    return cv.f;
}
__device__ __forceinline__ short f2bf(float x) {
    __hip_bfloat16 h = __float2bfloat16(x);
    union { __hip_bfloat16 h; short s; } cv; cv.h = h;
    return cv.s;
}

// ---------------------------------------------------------------------------
// Weight reorder -> Bw[oc'=hid*4+gate][k], bf16. Source oc = gate*64+hid.
// icx==1 (enc0): chunk0 = x-im2col taps (9 live of 64), chunks 1..9 = Wh taps.
// else: chunks 0..8 = Wx taps, 9..17 = Wh taps (64 ch each).
__global__ __launch_bounds__(256) void reorder_w(
    const float* __restrict__ Wx, int icx,
    const float* __restrict__ Wh, __hip_bfloat16* __restrict__ Bw, int ktot) {
    int ocp = blockIdx.x, hid = ocp >> 2, gate = ocp & 3;
    int oc = gate * 64 + hid;
    for (int k = threadIdx.x; k < ktot; k += 256) {
        int c = k >> 6, j = k & 63;
        float v;
        if (icx == 1) {
            if (c == 0) v = (j < 9) ? Wx[oc * 9 + j] : 0.0f;
            else        v = Wh[(oc * 64 + j) * 9 + (c - 1)];
        } else {
            if (c < 9)  v = Wx[(oc * 64 + j) * 9 + c];
            else        v = Wh[(oc * 64 + j) * 9 + (c - 9)];
        }
        Bw[ocp * ktot + k] = __float2bfloat16(v);
    }
}

// ---------------------------------------------------------------------------
// Pack Wc + bias -> wcb[hid*HW + p][8] bf16: [Wc g0..g3, bias g0..g3].
__global__ __launch_bounds__(256) void pack_wcb(
    const float* __restrict__ Wc, const float* __restrict__ bias,
    __hip_bfloat16* __restrict__ wcb) {
    int i = blockIdx.x * 256 + threadIdx.x;   // 0 .. HID*HW-1
    int hid = i >> 12, p = i & 4095;
    union { short s[8]; bf16x8 v; } u;
#pragma unroll
    for (int g = 0; g < 4; g++) {
        u.s[g]     = f2bf(Wc[(g * HID + hid) * HW + p]);
        u.s[4 + g] = f2bf(bias[(g * HID + hid) * HW + p]);
    }
    *(bf16x8*)&wcb[(size_t)i * 8] = u.v;
}

// ---------------------------------------------------------------------------
// im2col of x for ALL timesteps into padded NHWC bf16: ch 0..8 = 3x3 taps,
// ch 9..15 zero; ch 16..63 left as poison (only multiplied by zero weights).
__global__ __launch_bounds__(256) void pack_x_all(
    const float* __restrict__ x, __hip_bfloat16* __restrict__ px_all) {
    int i = blockIdx.x * 256 + threadIdx.x;   // 0 .. 10*8*4356-1
    if (i >= TSTEPS * BSZ * PPIX) return;
    int t = i / (BSZ * PPIX);
    int rem = i - t * (BSZ * PPIX);
    int b = rem / PPIX;
    int pp = rem - b * PPIX;
    int y = pp / PADW, xx = pp - y * PADW;    // padded coords 0..65
    int oy = y - 1, ox = xx - 1;
    const float* xb = x + ((size_t)(b * TSTEPS + t)) * HW;
    bool interior = (oy >= 0 && oy < 64 && ox >= 0 && ox < 64);
    union { short s[16]; bf16x8 v[2]; } u;
#pragma unroll
    for (int tap = 0; tap < 9; tap++) {
        int yy = oy + tap / 3 - 1, xc = ox + tap % 3 - 1;
        float val = (interior && yy >= 0 && yy < 64 && xc >= 0 && xc < 64)
                        ? xb[yy * 64 + xc] : 0.0f;
        u.s[tap] = f2bf(val);
    }
#pragma unroll
    for (int tap = 9; tap < 16; tap++) u.s[tap] = 0;
    short* o = (short*)(px_all + (size_t)t * PADSZ + ((size_t)(b * PPIX + pp)) * HID);
    *(bf16x8*)&o[0] = u.v[0];
    *(bf16x8*)&o[8] = u.v[1];
}

// ---------------------------------------------------------------------------
struct CellArgs {
    const __hip_bfloat16* Bw;
    const __hip_bfloat16* src0;
    const __hip_bfloat16* src1;
    const __hip_bfloat16* wcb;
    float* cbuf;
    __hip_bfloat16* hout;
    int ktot;   // 640 or 1152
    int n0;     // 1 or 9
    int first;  // skip c read (h(-1)=c(-1)=0)
};

// Fused im2col-GEMM + LSTM cell, barrier-light K-loop:
//   - B: one 4x66-pixel halo of the source staged into LDS per phase (2 stages,
//     3 barriers total). All 9 taps are ds_reads at shifted offsets.
//   - A: weight MFMA fragments loaded global->VGPR directly (L2 broadcast),
//     no LDS, no barrier; compiler pipelines loads across MFMAs via vmcnt.
// blockIdx.y in {0,1}: M-split (oc0). blockIdx.y==2: fused final_conv blocks
// for the previous decoder frame. blockIdx.z: one of two independent cell
// steps (encoder pipelining).
__global__ __launch_bounds__(256) void gemm_cell_fused(
    CellArgs A0, CellArgs A1,
    const __hip_bfloat16* fph, const float* fw, const float* fb,
    float* fout, int ff) {
    __shared__ short Hs[264 * 64];   // 33792 B: pixel halo / h-transpose reuse

    // ---- fused final_conv path (decoder only, y==2) ----
    if (blockIdx.y == 2) {
        int tid = threadIdx.x;
        if (tid < 128) {
            int p = blockIdx.x * 128 + tid;       // 0..32767
            int b = p >> 12, pp = p & 4095;
            int y = pp >> 6, x = pp & 63;
            float acc = fb[0];
#pragma unroll
            for (int tap = 0; tap < 9; tap++) {
                const bf16x8* base = (const bf16x8*)(
                    fph + ((size_t)(b * PADW + y + (tap / 3)) * PADW + (x + (tap % 3))) * HID);
#pragma unroll
                for (int c8 = 0; c8 < 8; c8++) {
                    bf16x8 v = base[c8];
#pragma unroll
                    for (int jj = 0; jj < 8; jj++)
                        acc = fmaf(bf2f(v[jj]), fw[(c8 * 8 + jj) * 9 + tap], acc);
                }
            }
            fout[((size_t)(b * FLEN + ff)) * HW + pp] = sigmoidf_(acc);
        }
        return;
    }

    const bool z1 = (blockIdx.z != 0);
    const __hip_bfloat16* __restrict__ src0 = z1 ? A1.src0 : A0.src0;
    const __hip_bfloat16* __restrict__ src1 = z1 ? A1.src1 : A0.src1;
    const __hip_bfloat16* __restrict__ wcb  = z1 ? A1.wcb  : A0.wcb;
    float* __restrict__ cbuf                = z1 ? A1.cbuf : A0.cbuf;
    __hip_bfloat16* __restrict__ hout       = z1 ? A1.hout : A0.hout;
    const short* __restrict__ BwS = (const short*)(z1 ? A1.Bw : A0.Bw);
    const int ktot  = z1 ? A1.ktot  : A0.ktot;
    const int n0    = z1 ? A1.n0    : A0.n0;
    const int first = z1 ? A1.first : A0.first;

    const int tid  = threadIdx.x;
    const int lane = tid & 63;
    const int wave = tid >> 6;
    const int quad = lane >> 4;
    const int l15  = lane & 15;
    const int wr = wave >> 1;
    const int wc = wave & 1;
    const int px0 = blockIdx.x * 128;
    const int oc0 = blockIdx.y * 128;
    const int bb = px0 >> 12;                 // batch
    const int y0 = (px0 & 4095) >> 6;         // first of 2 rows (even)

    // Per-lane A row base (elements) + per-lane fragment k-offsets.
    const int abase = (oc0 + wr * 64 + l15) * ktot;

    f32x4 acc[4][4] = {};

#pragma unroll
    for (int ph = 0; ph < 2; ph++) {
        const __hip_bfloat16* src = ph ? src1 : src0;
        const int cbase = ph ? n0 : 0;
        // ---- stage 4x66 pixel halo of src into LDS (swizzled channels) ----
        const short* sb = (const short*)src +
                          ((size_t)bb * PPIX + (size_t)y0 * PADW) * HID;
        if (ph) __syncthreads();              // all reads of prev halo done
#pragma unroll
        for (int r = 0; r < 9; r++) {
            int idx = r * 256 + tid;          // 0..2303; live < 2112
            if (idx < 2112) {                 // wave-uniform split (r==8: wave0)
                int hp = idx >> 3, seg = idx & 7;
                int segx = seg ^ (hp & 7);
                __builtin_amdgcn_global_load_lds(
                    (const __attribute__((address_space(1))) void*)(sb + hp * 64 + segx * 8),
                    (__attribute__((address_space(3))) void*)(&Hs[idx * 8]),
                    16, 0, 0);
            }
        }
        __syncthreads();

        // ---- taps: A from global, B from halo, no barriers ----
        if (n0 == 1 && ph == 0) {
            // single center tap, chunk 0
            const int chunk = 0;
#pragma unroll
            for (int k2 = 0; k2 < 2; k2++) {
                bf16x8 af[4], bfr[4];
#pragma unroll
                for (int i = 0; i < 4; i++)
                    af[i] = *(const bf16x8*)(BwS + abase + i * 16 * ktot +
                                             chunk * 64 + k2 * 32 + quad * 8);
#pragma unroll
                for (int j = 0; j < 4; j++) {
                    int pxl = wc * 64 + j * 16 + l15;
                    int hp = ((pxl >> 6) + 1) * PADW + (pxl & 63) + 1;
                    bfr[j] = *(const bf16x8*)&Hs[hp * 64 + (((k2 * 4 + quad) ^ (hp & 7))) * 8];
                }
#pragma unroll
                for (int i = 0; i < 4; i++)
#pragma unroll
                    for (int j = 0; j < 4; j++)
                        acc[i][j] = __builtin_amdgcn_mfma_f32_16x16x32_bf16(
                            af[i], bfr[j], acc[i][j], 0, 0, 0);
            }
        } else {
#pragma unroll
            for (int tap = 0; tap < 9; tap++) {
                const int dy = tap / 3, dx = tap % 3;
                const int chunk = cbase + tap;
#pragma unroll
                for (int k2 = 0; k2 < 2; k2++) {
                    bf16x8 af[4], bfr[4];
#pragma unroll
                    for (int i = 0; i < 4; i++)
                        af[i] = *(const bf16x8*)(BwS + abase + i * 16 * ktot +
                                                 chunk * 64 + k2 * 32 + quad * 8);
#pragma unroll
                    for (int j = 0; j < 4; j++) {
                        int pxl = wc * 64 + j * 16 + l15;
                        int hp = ((pxl >> 6) + dy) * PADW + (pxl & 63) + dx;
                        bfr[j] = *(const bf16x8*)&Hs[hp * 64 + (((k2 * 4 + quad) ^ (hp & 7))) * 8];
                    }
#pragma unroll
                    for (int i = 0; i < 4; i++)
#pragma unroll
                        for (int j = 0; j < 4; j++)
                            acc[i][j] = __builtin_amdgcn_mfma_f32_16x16x32_bf16(
                                af[i], bfr[j], acc[i][j], 0, 0, 0);
                }
            }
        }
    }

    // ---- Epilogue: in-register cell update; h transposed via LDS ----------
    __syncthreads();                          // halo reads done; reuse Hs
    short* hl = Hs;
    const int hid0 = oc0 >> 2;                // 0 or 32
#pragma unroll
    for (int i = 0; i < 4; i++) {
        int hidl = wr * 16 + i * 4 + quad;    // 0..31
        int hid = hid0 + hidl;
#pragma unroll
        for (int j = 0; j < 4; j++) {
            int pxl = wc * 64 + j * 16 + l15; // 0..127
            int px = px0 + pxl;
            int b = px >> 12, p = px & 4095;
            size_t ci = ((size_t)(b * HID + hid)) * HW + p;
            float cv = first ? 0.0f : cbuf[ci];
            bf16x8 wv = *(const bf16x8*)&wcb[((size_t)hid * HW + p) * 8];
            float pg[4];
#pragma unroll
            for (int r = 0; r < 4; r++)
                pg[r] = acc[i][j][r] + bf2f(wv[r]) * cv + bf2f(wv[4 + r]);
            float ig = sigmoidf_(pg[0]);
            float fg = sigmoidf_(pg[1]);
            float gg = tanh_fast(pg[2]);
            float og = sigmoidf_(pg[3]);
            float cn = fg * cv + ig * gg;
            cbuf[ci] = cn;
            float hn = og * tanh_fast(cn);
            hl[pxl * 40 + hidl] = f2bf(hn);
        }
    }
    __syncthreads();
#pragma unroll
    for (int rnd = 0; rnd < 2; rnd++) {
        int task = rnd * 256 + tid;           // 0..511
        int pxl = task >> 2, q = task & 3;
        bf16x8 v = *(const bf16x8*)&hl[pxl * 40 + q * 8];
        int px = px0 + pxl;
        int b = px >> 12, p = px & 4095, y = p >> 6, x = p & 63;
        *(bf16x8*)&hout[((size_t)((b * PADW + y + 1) * PADW + (x + 1))) * HID
                        + hid0 + q * 8] = v;
    }
}

// ---------------------------------------------------------------------------
// Standalone final conv (used for the last frame only).
__global__ __launch_bounds__(256) void final_conv(
    const __hip_bfloat16* __restrict__ ph, const float* __restrict__ fw,
    const float* __restrict__ fb, float* __restrict__ out, int f) {
    int b = blockIdx.y;
    int p = blockIdx.x * 256 + threadIdx.x;
    int y = p >> 6, x = p & 63;
    float acc = fb[0];
#pragma unroll
    for (int tap = 0; tap < 9; tap++) {
        const bf16x8* base = (const bf16x8*)(
            ph + ((b * PADW + y + (tap / 3)) * PADW + (x + (tap % 3))) * HID);
#pragma unroll
        for (int c8 = 0; c8 < 8; c8++) {
            bf16x8 v = base[c8];
#pragma unroll
            for (int jj = 0; jj < 8; jj++)
                acc = fmaf(bf2f(v[jj]), fw[(c8 * 8 + jj) * 9 + tap], acc);
        }
    }
    out[((size_t)(b * FLEN + f)) * HW + p] = sigmoidf_(acc);
}

// ---------------------------------------------------------------------------
extern "C" void kernel_launch(void* const* d_in, const int* in_sizes, int n_in,
                              void* d_out, int out_size, void* d_ws, size_t ws_size,
                              hipStream_t stream) {
    const float* x = (const float*)d_in[0];
    const float* Wx_[4] = {(const float*)d_in[1], (const float*)d_in[5],
                           (const float*)d_in[9], (const float*)d_in[13]};
    const float* Wh_[4] = {(const float*)d_in[2], (const float*)d_in[6],
                           (const float*)d_in[10], (const float*)d_in[14]};
    const float* Wc_[4] = {(const float*)d_in[3], (const float*)d_in[7],
                           (const float*)d_in[11], (const float*)d_in[15]};
    const float* b_[4]  = {(const float*)d_in[4], (const float*)d_in[8],
                           (const float*)d_in[12], (const float*)d_in[16]};
    const float* fin_w  = (const float*)d_in[17];
    const float* fin_b  = (const float*)d_in[18];
    float* out = (float*)d_out;

    char* wsb = (char*)d_ws;
    const size_t H_BYTES  = 8ull * PADSZ * sizeof(short);       // 35,684,352
    const size_t PX_BYTES = 10ull * PADSZ * sizeof(short);      // 44,605,440
    const size_t C_BYTES  = 4ull * SB * sizeof(float);          // 33,554,432
    const size_t WCB_ELEM = (size_t)HID * HW * 8;               // per cell

    __hip_bfloat16* hb = (__hip_bfloat16*)wsb;
    __hip_bfloat16* px_all = (__hip_bfloat16*)(wsb + H_BYTES);
    float* cbuf = (float*)(wsb + H_BYTES + PX_BYTES);
    __hip_bfloat16* wcb = (__hip_bfloat16*)(wsb + H_BYTES + PX_BYTES + C_BYTES);
    __hip_bfloat16* bw = wcb + 4 * WCB_ELEM;

    __hip_bfloat16* e0buf[2] = {hb + 0 * (size_t)PADSZ, hb + 1 * (size_t)PADSZ};
    __hip_bfloat16* e1buf[2] = {hb + 2 * (size_t)PADSZ, hb + 3 * (size_t)PADSZ};
    __hip_bfloat16* d0buf[2] = {hb + 4 * (size_t)PADSZ, hb + 5 * (size_t)PADSZ};
    __hip_bfloat16* d1buf[2] = {hb + 6 * (size_t)PADSZ, hb + 7 * (size_t)PADSZ};

    float* c_[4] = {cbuf, cbuf + (size_t)SB, cbuf + 2 * (size_t)SB, cbuf + 3 * (size_t)SB};
    __hip_bfloat16* wcb_[4] = {wcb, wcb + WCB_ELEM, wcb + 2 * WCB_ELEM, wcb + 3 * WCB_ELEM};
    __hip_bfloat16* bw_e0 = bw;
    __hip_bfloat16* bw_e1 = bw_e0 + (size_t)OC4 * KT_E0;
    __hip_bfloat16* bw_d0 = bw_e1 + (size_t)OC4 * KT_STD;
    __hip_bfloat16* bw_d1 = bw_d0 + (size_t)OC4 * KT_STD;
    __hip_bfloat16* bw_[4] = {bw_e0, bw_e1, bw_d0, bw_d1};

    hipMemsetAsync(wsb, 0, H_BYTES, stream);

    reorder_w<<<dim3(OC4), 256, 0, stream>>>(Wx_[0], 1,   Wh_[0], bw_e0, KT_E0);
    reorder_w<<<dim3(OC4), 256, 0, stream>>>(Wx_[1], HID, Wh_[1], bw_e1, KT_STD);
    reorder_w<<<dim3(OC4), 256, 0, stream>>>(Wx_[2], HID, Wh_[2], bw_d0, KT_STD);
    reorder_w<<<dim3(OC4), 256, 0, stream>>>(Wx_[3], HID, Wh_[3], bw_d1, KT_STD);
    for (int cix = 0; cix < 4; cix++)
        pack_wcb<<<dim3((HID * HW) / 256), 256, 0, stream>>>(Wc_[cix], b_[cix], wcb_[cix]);
    pack_x_all<<<dim3((TSTEPS * BSZ * PPIX + 255) / 256), 256, 0, stream>>>(x, px_all);

    auto cellargs = [&](int cell, const __hip_bfloat16* s0, const __hip_bfloat16* s1,
                        __hip_bfloat16* ho, int kt, int nn0, int fi) {
        CellArgs a;
        a.Bw = bw_[cell]; a.src0 = s0; a.src1 = s1; a.wcb = wcb_[cell];
        a.cbuf = c_[cell]; a.hout = ho; a.ktot = kt; a.n0 = nn0; a.first = fi;
        return a;
    };
    auto px = [&](int t) { return px_all + (size_t)t * PADSZ; };

    // --- Encoder, software-pipelined: dispatch k runs enc0(t=k) || enc1(t=k-1).
    {
        CellArgs a = cellargs(0, px(0), e0buf[1], e0buf[0], KT_E0, 1, 1);
        gemm_cell_fused<<<dim3(256, 2, 1), 256, 0, stream>>>(
            a, a, (const __hip_bfloat16*)nullptr, fin_w, fin_b, out, 0);
    }
    for (int k = 1; k <= 9; k++) {
        int t0 = k, t1 = k - 1;
        CellArgs a0 = cellargs(0, px(t0), e0buf[(t0 - 1) & 1], e0buf[t0 & 1],
                               KT_E0, 1, 0);
        CellArgs a1 = cellargs(1, e0buf[t1 & 1], e1buf[(t1 - 1) & 1], e1buf[t1 & 1],
                               KT_STD, 9, (t1 == 0) ? 1 : 0);
        gemm_cell_fused<<<dim3(256, 2, 2), 256, 0, stream>>>(
            a0, a1, (const __hip_bfloat16*)nullptr, fin_w, fin_b, out, 0);
    }
    {
        CellArgs a = cellargs(1, e0buf[1], e1buf[0], e1buf[1], KT_STD, 9, 0); // t=9
        gemm_cell_fused<<<dim3(256, 2, 1), 256, 0, stream>>>(
            a, a, (const __hip_bfloat16*)nullptr, fin_w, fin_b, out, 0);
    }
    __hip_bfloat16* enc_top = e1buf[1];   // e1h(9)

    // --- Decoder: dec0(f) carries fused final_conv for frame f-1 (y==2 blocks).
    for (int f = 0; f < FLEN; f++) {
        const __hip_bfloat16* s = (f == 0) ? enc_top : d1buf[(f - 1) & 1];
        CellArgs a0 = cellargs(2, s, d0buf[(f - 1) & 1], d0buf[f & 1],
                               KT_STD, 9, (f == 0) ? 1 : 0);
        if (f == 0) {
            gemm_cell_fused<<<dim3(256, 2, 1), 256, 0, stream>>>(
                a0, a0, (const __hip_bfloat16*)nullptr, fin_w, fin_b, out, 0);
        } else {
            gemm_cell_fused<<<dim3(256, 3, 1), 256, 0, stream>>>(
                a0, a0, d1buf[(f - 1) & 1], fin_w, fin_b, out, f - 1);
        }
        CellArgs a1 = cellargs(3, d0buf[f & 1], d1buf[(f - 1) & 1], d1buf[f & 1],
                               KT_STD, 9, (f == 0) ? 1 : 0);
        gemm_cell_fused<<<dim3(256, 2, 1), 256, 0, stream>>>(
            a1, a1, (const __hip_bfloat16*)nullptr, fin_w, fin_b, out, 0);
    }
    final_conv<<<dim3(16, BSZ), 256, 0, stream>>>(d1buf[1], fin_w, fin_b, out, 9);
}

// Round 6
// 1865.627 us; speedup vs baseline: 1.5199x; 1.5199x over previous
//
#include <hip/hip_runtime.h>
#include <hip/hip_bf16.h>
#include <math.h>

// Problem constants (fixed by setup_inputs)
#define BSZ    8
#define TSTEPS 10
#define FLEN   10
#define HID    64
#define HW     4096                 // 64*64
#define IMG    (HID * HW)           // 262144
#define OC4    (4 * HID)            // 256 gate channels
#define PADW   66
#define PPIX   (PADW * PADW)        // 4356
#define PADIMG (PPIX * HID)         // padded NHWC plane per batch
#define PADSZ  (BSZ * PADIMG)       // 2230272 bf16 elems per buffer
#define SB     (BSZ * IMG)          // 2097152 floats (one c state)
#define KT_E0  640                  // enc0: 1 x-im2col chunk + 9 h chunks
#define KT_STD 1152                 // 9 x chunks + 9 h chunks

typedef __attribute__((ext_vector_type(8))) short bf16x8;
typedef __attribute__((ext_vector_type(4))) float f32x4;

__device__ __forceinline__ float sigmoidf_(float x) {
    return 1.0f / (1.0f + __expf(-x));
}
__device__ __forceinline__ float tanh_fast(float x) {
    float e = __expf(2.0f * x);
    return 1.0f - 2.0f / (e + 1.0f);     // exact at +-inf saturation
}
__device__ __forceinline__ float bf2f(short u) {
    union { unsigned u; float f; } cv;
    cv.u = ((unsigned)(unsigned short)u) << 16;
    return cv.f;
}
__device__ __forceinline__ short f2bf(float x) {
    __hip_bfloat16 h = __float2bfloat16(x);
    union { __hip_bfloat16 h; short s; } cv; cv.h = h;
    return cv.s;
}

// ---------------------------------------------------------------------------
// Weight reorder into MFMA **A-fragment order**:
//   Aswz[((chunk*16 + tile)*2 + k2)*512 + lane*8 + jj]
//     = W[oc' = tile*16 + (lane&15)][k = chunk*64 + k2*32 + (lane>>4)*8 + jj]
// where oc' = hid*4+gate (source oc = gate*64+hid), W = [Wx taps | Wh taps]
// (enc0: chunk0 = x-im2col taps, 9 live of 64; chunks 1..9 = Wh taps).
// A wave's fragment load is then one contiguous 1KB dwordx4 across lanes.
__global__ __launch_bounds__(256) void reorder_w_swz(
    const float* __restrict__ Wx, int icx,
    const float* __restrict__ Wh, __hip_bfloat16* __restrict__ Bw, int ktot) {
    int gid = blockIdx.x * 256 + threadIdx.x;   // one thread per 8 elems
    int lane = gid & 63;
    int g = gid >> 6;
    int k2 = g & 1; g >>= 1;
    int tile = g & 15; g >>= 4;
    int chunk = g;                              // < ktot/64
    int quad = lane >> 4, l15 = lane & 15;
    int ocp = tile * 16 + l15;
    int hid = ocp >> 2, gate = ocp & 3;
    int oc = gate * 64 + hid;
    short o8[8];
#pragma unroll
    for (int jj = 0; jj < 8; jj++) {
        int j = k2 * 32 + quad * 8 + jj;        // k within chunk (0..63)
        float v;
        if (icx == 1) {
            if (chunk == 0) v = (j < 9) ? Wx[oc * 9 + j] : 0.0f;
            else            v = Wh[(oc * 64 + j) * 9 + (chunk - 1)];
        } else {
            if (chunk < 9)  v = Wx[(oc * 64 + j) * 9 + chunk];
            else            v = Wh[(oc * 64 + j) * 9 + (chunk - 9)];
        }
        o8[jj] = f2bf(v);
    }
    *(bf16x8*)&((short*)Bw)[(size_t)gid * 8] = *(bf16x8*)o8;
}

// ---------------------------------------------------------------------------
// Pack Wc + bias -> wcb[hid*HW + p][8] bf16: [Wc g0..g3, bias g0..g3].
__global__ __launch_bounds__(256) void pack_wcb(
    const float* __restrict__ Wc, const float* __restrict__ bias,
    __hip_bfloat16* __restrict__ wcb) {
    int i = blockIdx.x * 256 + threadIdx.x;   // 0 .. HID*HW-1
    int hid = i >> 12, p = i & 4095;
    union { short s[8]; bf16x8 v; } u;
#pragma unroll
    for (int g = 0; g < 4; g++) {
        u.s[g]     = f2bf(Wc[(g * HID + hid) * HW + p]);
        u.s[4 + g] = f2bf(bias[(g * HID + hid) * HW + p]);
    }
    *(bf16x8*)&wcb[(size_t)i * 8] = u.v;
}

// ---------------------------------------------------------------------------
// im2col of x for ALL timesteps into padded NHWC bf16: ch 0..8 = 3x3 taps,
// ch 9..15 zero; ch 16..63 left as poison (only multiplied by zero weights).
__global__ __launch_bounds__(256) void pack_x_all(
    const float* __restrict__ x, __hip_bfloat16* __restrict__ px_all) {
    int i = blockIdx.x * 256 + threadIdx.x;   // 0 .. 10*8*4356-1
    if (i >= TSTEPS * BSZ * PPIX) return;
    int t = i / (BSZ * PPIX);
    int rem = i - t * (BSZ * PPIX);
    int b = rem / PPIX;
    int pp = rem - b * PPIX;
    int y = pp / PADW, xx = pp - y * PADW;    // padded coords 0..65
    int oy = y - 1, ox = xx - 1;
    const float* xb = x + ((size_t)(b * TSTEPS + t)) * HW;
    bool interior = (oy >= 0 && oy < 64 && ox >= 0 && ox < 64);
    union { short s[16]; bf16x8 v[2]; } u;
#pragma unroll
    for (int tap = 0; tap < 9; tap++) {
        int yy = oy + tap / 3 - 1, xc = ox + tap % 3 - 1;
        float val = (interior && yy >= 0 && yy < 64 && xc >= 0 && xc < 64)
                        ? xb[yy * 64 + xc] : 0.0f;
        u.s[tap] = f2bf(val);
    }
#pragma unroll
    for (int tap = 9; tap < 16; tap++) u.s[tap] = 0;
    short* o = (short*)(px_all + (size_t)t * PADSZ + ((size_t)(b * PPIX + pp)) * HID);
    *(bf16x8*)&o[0] = u.v[0];
    *(bf16x8*)&o[8] = u.v[1];
}

// ---------------------------------------------------------------------------
struct CellArgs {
    const __hip_bfloat16* Bw;    // fragment-swizzled weights
    const __hip_bfloat16* src0;
    const __hip_bfloat16* src1;
    const __hip_bfloat16* wcb;
    float* cbuf;
    __hip_bfloat16* hout;
    int ktot;   // 640 or 1152
    int n0;     // 1 or 9
    int first;  // skip c read (h(-1)=c(-1)=0)
};

// Fused im2col-GEMM + LSTM cell, barrier-light K-loop:
//   - B: one 4x66-pixel halo of the source staged into LDS per phase (2 stages,
//     3 barriers total). All 9 taps are ds_reads at shifted offsets.
//   - A: weights pre-swizzled into MFMA fragment order -> each fragment is a
//     coalesced 1KB global_load_dwordx4 per wave (L2-resident), no LDS/barrier.
// blockIdx.y in {0,1}: M-split (oc0). blockIdx.y==2: fused final_conv blocks
// for the previous decoder frame. blockIdx.z: one of two independent cell
// steps (encoder pipelining).
__global__ __launch_bounds__(256, 3) void gemm_cell_fused(
    CellArgs A0, CellArgs A1,
    const __hip_bfloat16* fph, const float* fw, const float* fb,
    float* fout, int ff) {
    __shared__ short Hs[264 * 64];   // 33792 B: pixel halo / h-transpose reuse

    // ---- fused final_conv path (decoder only, y==2) ----
    if (blockIdx.y == 2) {
        int tid = threadIdx.x;
        if (tid < 128) {
            int p = blockIdx.x * 128 + tid;       // 0..32767
            int b = p >> 12, pp = p & 4095;
            int y = pp >> 6, x = pp & 63;
            float acc = fb[0];
#pragma unroll
            for (int tap = 0; tap < 9; tap++) {
                const bf16x8* base = (const bf16x8*)(
                    fph + ((size_t)(b * PADW + y + (tap / 3)) * PADW + (x + (tap % 3))) * HID);
#pragma unroll
                for (int c8 = 0; c8 < 8; c8++) {
                    bf16x8 v = base[c8];
#pragma unroll
                    for (int jj = 0; jj < 8; jj++)
                        acc = fmaf(bf2f(v[jj]), fw[(c8 * 8 + jj) * 9 + tap], acc);
                }
            }
            fout[((size_t)(b * FLEN + ff)) * HW + pp] = sigmoidf_(acc);
        }
        return;
    }

    const bool z1 = (blockIdx.z != 0);
    const __hip_bfloat16* __restrict__ src0 = z1 ? A1.src0 : A0.src0;
    const __hip_bfloat16* __restrict__ src1 = z1 ? A1.src1 : A0.src1;
    const __hip_bfloat16* __restrict__ wcb  = z1 ? A1.wcb  : A0.wcb;
    float* __restrict__ cbuf                = z1 ? A1.cbuf : A0.cbuf;
    __hip_bfloat16* __restrict__ hout       = z1 ? A1.hout : A0.hout;
    const short* __restrict__ BwS = (const short*)(z1 ? A1.Bw : A0.Bw);
    const int n0    = z1 ? A1.n0    : A0.n0;
    const int first = z1 ? A1.first : A0.first;

    const int tid  = threadIdx.x;
    const int lane = tid & 63;
    const int wave = tid >> 6;
    const int quad = lane >> 4;
    const int l15  = lane & 15;
    const int wr = wave >> 1;
    const int wc = wave & 1;
    const int px0 = blockIdx.x * 128;
    const int oc0 = blockIdx.y * 128;
    const int bb = px0 >> 12;                 // batch
    const int y0 = (px0 & 4095) >> 6;         // first of 2 rows (even)
    const int tbase = (oc0 >> 4) + wr * 4;    // first A-tile of this wave

    f32x4 acc[4][4] = {};

#pragma unroll
    for (int ph = 0; ph < 2; ph++) {
        const __hip_bfloat16* src = ph ? src1 : src0;
        const int cbase = ph ? n0 : 0;
        // ---- stage 4x66 pixel halo of src into LDS (swizzled channels) ----
        const short* sb = (const short*)src +
                          ((size_t)bb * PPIX + (size_t)y0 * PADW) * HID;
        if (ph) __syncthreads();              // all reads of prev halo done
#pragma unroll
        for (int r = 0; r < 9; r++) {
            int idx = r * 256 + tid;          // 0..2303; live < 2112
            if (idx < 2112) {                 // wave-uniform split (r==8: wave0)
                int hp = idx >> 3, seg = idx & 7;
                int segx = seg ^ (hp & 7);
                __builtin_amdgcn_global_load_lds(
                    (const __attribute__((address_space(1))) void*)(sb + hp * 64 + segx * 8),
                    (__attribute__((address_space(3))) void*)(&Hs[idx * 8]),
                    16, 0, 0);
            }
        }
        __syncthreads();

        // ---- taps: A coalesced from global (fragment order), B from halo ----
        const int tap_lo = (n0 == 1 && ph == 0) ? 4 : 0;   // enc0 phase0: center only
        const int tap_hi = (n0 == 1 && ph == 0) ? 5 : 9;
        for (int tap = tap_lo; tap < tap_hi; tap++) {
            const int dy = tap / 3, dx = tap % 3;
            const int chunk = (n0 == 1 && ph == 0) ? 0 : cbase + tap;
#pragma unroll
            for (int k2 = 0; k2 < 2; k2++) {
                bf16x8 af[4], bfr[4];
#pragma unroll
                for (int i = 0; i < 4; i++)
                    af[i] = *(const bf16x8*)(BwS +
                        ((((size_t)chunk * 16 + tbase + i) * 2 + k2) << 9) + (lane << 3));
#pragma unroll
                for (int j = 0; j < 4; j++) {
                    int pxl = wc * 64 + j * 16 + l15;
                    int hp = ((pxl >> 6) + dy) * PADW + (pxl & 63) + dx;
                    bfr[j] = *(const bf16x8*)&Hs[hp * 64 + (((k2 * 4 + quad) ^ (hp & 7))) * 8];
                }
#pragma unroll
                for (int i = 0; i < 4; i++)
#pragma unroll
                    for (int j = 0; j < 4; j++)
                        acc[i][j] = __builtin_amdgcn_mfma_f32_16x16x32_bf16(
                            af[i], bfr[j], acc[i][j], 0, 0, 0);
            }
        }
    }

    // ---- Epilogue: in-register cell update; h transposed via LDS ----------
    __syncthreads();                          // halo reads done; reuse Hs
    short* hl = Hs;
    const int hid0 = oc0 >> 2;                // 0 or 32
#pragma unroll
    for (int i = 0; i < 4; i++) {
        int hidl = wr * 16 + i * 4 + quad;    // 0..31
        int hid = hid0 + hidl;
#pragma unroll
        for (int j = 0; j < 4; j++) {
            int pxl = wc * 64 + j * 16 + l15; // 0..127
            int px = px0 + pxl;
            int b = px >> 12, p = px & 4095;
            size_t ci = ((size_t)(b * HID + hid)) * HW + p;
            float cv = first ? 0.0f : cbuf[ci];
            bf16x8 wv = *(const bf16x8*)&wcb[((size_t)hid * HW + p) * 8];
            float pg[4];
#pragma unroll
            for (int r = 0; r < 4; r++)
                pg[r] = acc[i][j][r] + bf2f(wv[r]) * cv + bf2f(wv[4 + r]);
            float ig = sigmoidf_(pg[0]);
            float fg = sigmoidf_(pg[1]);
            float gg = tanh_fast(pg[2]);
            float og = sigmoidf_(pg[3]);
            float cn = fg * cv + ig * gg;
            cbuf[ci] = cn;
            float hn = og * tanh_fast(cn);
            hl[pxl * 40 + hidl] = f2bf(hn);
        }
    }
    __syncthreads();
#pragma unroll
    for (int rnd = 0; rnd < 2; rnd++) {
        int task = rnd * 256 + tid;           // 0..511
        int pxl = task >> 2, q = task & 3;
        bf16x8 v = *(const bf16x8*)&hl[pxl * 40 + q * 8];
        int px = px0 + pxl;
        int b = px >> 12, p = px & 4095, y = p >> 6, x = p & 63;
        *(bf16x8*)&hout[((size_t)((b * PADW + y + 1) * PADW + (x + 1))) * HID
                        + hid0 + q * 8] = v;
    }
}

// ---------------------------------------------------------------------------
// Standalone final conv (used for the last frame only).
__global__ __launch_bounds__(256) void final_conv(
    const __hip_bfloat16* __restrict__ ph, const float* __restrict__ fw,
    const float* __restrict__ fb, float* __restrict__ out, int f) {
    int b = blockIdx.y;
    int p = blockIdx.x * 256 + threadIdx.x;
    int y = p >> 6, x = p & 63;
    float acc = fb[0];
#pragma unroll
    for (int tap = 0; tap < 9; tap++) {
        const bf16x8* base = (const bf16x8*)(
            ph + ((b * PADW + y + (tap / 3)) * PADW + (x + (tap % 3))) * HID);
#pragma unroll
        for (int c8 = 0; c8 < 8; c8++) {
            bf16x8 v = base[c8];
#pragma unroll
            for (int jj = 0; jj < 8; jj++)
                acc = fmaf(bf2f(v[jj]), fw[(c8 * 8 + jj) * 9 + tap], acc);
        }
    }
    out[((size_t)(b * FLEN + f)) * HW + p] = sigmoidf_(acc);
}

// ---------------------------------------------------------------------------
extern "C" void kernel_launch(void* const* d_in, const int* in_sizes, int n_in,
                              void* d_out, int out_size, void* d_ws, size_t ws_size,
                              hipStream_t stream) {
    const float* x = (const float*)d_in[0];
    const float* Wx_[4] = {(const float*)d_in[1], (const float*)d_in[5],
                           (const float*)d_in[9], (const float*)d_in[13]};
    const float* Wh_[4] = {(const float*)d_in[2], (const float*)d_in[6],
                           (const float*)d_in[10], (const float*)d_in[14]};
    const float* Wc_[4] = {(const float*)d_in[3], (const float*)d_in[7],
                           (const float*)d_in[11], (const float*)d_in[15]};
    const float* b_[4]  = {(const float*)d_in[4], (const float*)d_in[8],
                           (const float*)d_in[12], (const float*)d_in[16]};
    const float* fin_w  = (const float*)d_in[17];
    const float* fin_b  = (const float*)d_in[18];
    float* out = (float*)d_out;

    char* wsb = (char*)d_ws;
    const size_t H_BYTES  = 8ull * PADSZ * sizeof(short);       // 35,684,352
    const size_t PX_BYTES = 10ull * PADSZ * sizeof(short);      // 44,605,440
    const size_t C_BYTES  = 4ull * SB * sizeof(float);          // 33,554,432
    const size_t WCB_ELEM = (size_t)HID * HW * 8;               // per cell

    __hip_bfloat16* hb = (__hip_bfloat16*)wsb;
    __hip_bfloat16* px_all = (__hip_bfloat16*)(wsb + H_BYTES);
    float* cbuf = (float*)(wsb + H_BYTES + PX_BYTES);
    __hip_bfloat16* wcb = (__hip_bfloat16*)(wsb + H_BYTES + PX_BYTES + C_BYTES);
    __hip_bfloat16* bw = wcb + 4 * WCB_ELEM;

    __hip_bfloat16* e0buf[2] = {hb + 0 * (size_t)PADSZ, hb + 1 * (size_t)PADSZ};
    __hip_bfloat16* e1buf[2] = {hb + 2 * (size_t)PADSZ, hb + 3 * (size_t)PADSZ};
    __hip_bfloat16* d0buf[2] = {hb + 4 * (size_t)PADSZ, hb + 5 * (size_t)PADSZ};
    __hip_bfloat16* d1buf[2] = {hb + 6 * (size_t)PADSZ, hb + 7 * (size_t)PADSZ};

    float* c_[4] = {cbuf, cbuf + (size_t)SB, cbuf + 2 * (size_t)SB, cbuf + 3 * (size_t)SB};
    __hip_bfloat16* wcb_[4] = {wcb, wcb + WCB_ELEM, wcb + 2 * WCB_ELEM, wcb + 3 * WCB_ELEM};
    __hip_bfloat16* bw_e0 = bw;
    __hip_bfloat16* bw_e1 = bw_e0 + (size_t)OC4 * KT_E0;
    __hip_bfloat16* bw_d0 = bw_e1 + (size_t)OC4 * KT_STD;
    __hip_bfloat16* bw_d1 = bw_d0 + (size_t)OC4 * KT_STD;
    __hip_bfloat16* bw_[4] = {bw_e0, bw_e1, bw_d0, bw_d1};

    hipMemsetAsync(wsb, 0, H_BYTES, stream);

    reorder_w_swz<<<dim3(KT_E0 / 8), 256, 0, stream>>>(Wx_[0], 1,   Wh_[0], bw_e0, KT_E0);
    reorder_w_swz<<<dim3(KT_STD / 8), 256, 0, stream>>>(Wx_[1], HID, Wh_[1], bw_e1, KT_STD);
    reorder_w_swz<<<dim3(KT_STD / 8), 256, 0, stream>>>(Wx_[2], HID, Wh_[2], bw_d0, KT_STD);
    reorder_w_swz<<<dim3(KT_STD / 8), 256, 0, stream>>>(Wx_[3], HID, Wh_[3], bw_d1, KT_STD);
    for (int cix = 0; cix < 4; cix++)
        pack_wcb<<<dim3((HID * HW) / 256), 256, 0, stream>>>(Wc_[cix], b_[cix], wcb_[cix]);
    pack_x_all<<<dim3((TSTEPS * BSZ * PPIX + 255) / 256), 256, 0, stream>>>(x, px_all);

    auto cellargs = [&](int cell, const __hip_bfloat16* s0, const __hip_bfloat16* s1,
                        __hip_bfloat16* ho, int kt, int nn0, int fi) {
        CellArgs a;
        a.Bw = bw_[cell]; a.src0 = s0; a.src1 = s1; a.wcb = wcb_[cell];
        a.cbuf = c_[cell]; a.hout = ho; a.ktot = kt; a.n0 = nn0; a.first = fi;
        return a;
    };
    auto px = [&](int t) { return px_all + (size_t)t * PADSZ; };

    // --- Encoder, software-pipelined: dispatch k runs enc0(t=k) || enc1(t=k-1).
    {
        CellArgs a = cellargs(0, px(0), e0buf[1], e0buf[0], KT_E0, 1, 1);
        gemm_cell_fused<<<dim3(256, 2, 1), 256, 0, stream>>>(
            a, a, (const __hip_bfloat16*)nullptr, fin_w, fin_b, out, 0);
    }
    for (int k = 1; k <= 9; k++) {
        int t0 = k, t1 = k - 1;
        CellArgs a0 = cellargs(0, px(t0), e0buf[(t0 - 1) & 1], e0buf[t0 & 1],
                               KT_E0, 1, 0);
        CellArgs a1 = cellargs(1, e0buf[t1 & 1], e1buf[(t1 - 1) & 1], e1buf[t1 & 1],
                               KT_STD, 9, (t1 == 0) ? 1 : 0);
        gemm_cell_fused<<<dim3(256, 2, 2), 256, 0, stream>>>(
            a0, a1, (const __hip_bfloat16*)nullptr, fin_w, fin_b, out, 0);
    }
    {
        CellArgs a = cellargs(1, e0buf[1], e1buf[0], e1buf[1], KT_STD, 9, 0); // t=9
        gemm_cell_fused<<<dim3(256, 2, 1), 256, 0, stream>>>(
            a, a, (const __hip_bfloat16*)nullptr, fin_w, fin_b, out, 0);
    }
    __hip_bfloat16* enc_top = e1buf[1];   // e1h(9)

    // --- Decoder: dec0(f) carries fused final_conv for frame f-1 (y==2 blocks).
    for (int f = 0; f < FLEN; f++) {
        const __hip_bfloat16* s = (f == 0) ? enc_top : d1buf[(f - 1) & 1];
        CellArgs a0 = cellargs(2, s, d0buf[(f - 1) & 1], d0buf[f & 1],
                               KT_STD, 9, (f == 0) ? 1 : 0);
        if (f == 0) {
            gemm_cell_fused<<<dim3(256, 2, 1), 256, 0, stream>>>(
                a0, a0, (const __hip_bfloat16*)nullptr, fin_w, fin_b, out, 0);
        } else {
            gemm_cell_fused<<<dim3(256, 3, 1), 256, 0, stream>>>(
                a0, a0, d1buf[(f - 1) & 1], fin_w, fin_b, out, f - 1);
        }
        CellArgs a1 = cellargs(3, d0buf[f & 1], d1buf[(f - 1) & 1], d1buf[f & 1],
                               KT_STD, 9, (f == 0) ? 1 : 0);
        gemm_cell_fused<<<dim3(256, 2, 1), 256, 0, stream>>>(
            a1, a1, (const __hip_bfloat16*)nullptr, fin_w, fin_b, out, 0);
    }
    final_conv<<<dim3(16, BSZ), 256, 0, stream>>>(d1buf[1], fin_w, fin_b, out, 9);
}